// Round 1
// baseline (1037.725 us; speedup 1.0000x reference)
//
#include <hip/hip_runtime.h>
#include <stdint.h>
#include <stddef.h>

typedef __attribute__((ext_vector_type(8))) short short8;
typedef __attribute__((ext_vector_type(4))) float f32x4;
typedef __attribute__((ext_vector_type(4))) unsigned int u32x4;

#define B_ 4
#define L_ 8192
#define D_ 1024
#define BL 32768  // B_*L_

// round-to-nearest-even fp32 -> bf16 bits
__device__ __forceinline__ unsigned bf16rne(float v){
  unsigned u = __float_as_uint(v);
  return (u + 0x7fffu + ((u >> 16) & 1u)) >> 16;
}

// load 8 consecutive f32 (32B-aligned), split into hi/lo bf16 packed pairs
__device__ __forceinline__ void cvt8(const float* __restrict__ src, u32x4& hp, u32x4& lp){
  float v[8];
  *(f32x4*)(v)     = *(const f32x4*)(src);
  *(f32x4*)(v + 4) = *(const f32x4*)(src + 4);
  unsigned hb[8], lb[8];
  #pragma unroll
  for (int j = 0; j < 8; ++j){
    hb[j] = bf16rne(v[j]);
    float hif = __uint_as_float(hb[j] << 16);
    lb[j] = bf16rne(v[j] - hif);
  }
  #pragma unroll
  for (int t = 0; t < 4; ++t){
    hp[t] = hb[2*t] | (hb[2*t+1] << 16);
    lp[t] = lb[2*t] | (lb[2*t+1] << 16);
  }
}

// ---------------------------------------------------------------------------
// K1: fused dual-GEMM (q = x Wq^T, k = x Wk^T) with immediate reduction to
// per-row scalars: dot(q[l], k[l-1]), |q[l]|^2, |k[l-1]|^2.
// bf16 hi/lo split, 3-term (hh + hl + lh) MFMA per product.
// Grid: (256 row-strips of 128) x (2 e-halves of 512 cols). 4 waves/block,
// each wave owns 32 rows (two 16-row M-tiles).
// ---------------------------------------------------------------------------
__launch_bounds__(256, 2)
__global__ void k1_qkdot(const float* __restrict__ x, const float* __restrict__ Wq,
                         const float* __restrict__ Wk,
                         float* __restrict__ dotS, float* __restrict__ nqS,
                         float* __restrict__ nkS)
{
  // per LDS row: 128 B = [hi k0..31 | lo k0..31] bf16, XOR-swizzled in 16B chunks
  __shared__ __align__(16) unsigned short lds[(129 + 64 + 64) * 64];
  unsigned short* xhl = lds;               // 129 rows (strip rows row0-1 .. row0+127)
  unsigned short* wqp = lds + 129 * 64;    // 64 e-cols
  unsigned short* wkp = wqp + 64 * 64;     // 64 e-cols

  const int tid   = threadIdx.x;
  const int strip = blockIdx.x;            // 0..255
  const int eh    = blockIdx.y;            // 0..1
  const int row0  = strip << 7;
  const int firstAdj = ((row0 & (L_ - 1)) == 0) ? 1 : 0;  // batch-start: clamp row -1

  const int lane  = tid & 63;
  const int wv    = tid >> 6;
  const int laneR = lane & 15;
  const int laneG = lane >> 4;
  const int kb2   = laneG << 4;            // byte offset of this lane's k-base (8 bf16)

  // A-fragment LDS byte offsets (constant across k-steps; tile buffer is reused)
  int aoq[2], aok[2];
  #pragma unroll
  for (int mt = 0; mt < 2; ++mt){
    const int qrow = wv * 32 + mt * 16 + laneR + 1;  // LDS row of q-row (global l)
    const int krow = qrow - 1;                        // LDS row of k-row (global l-1)
    aoq[mt] = qrow * 128 + (kb2 ^ ((qrow & 7) << 4));
    aok[mt] = krow * 128 + (kb2 ^ ((krow & 7) << 4));
  }
  int bo[4];
  #pragma unroll
  for (int n = 0; n < 4; ++n){
    const int col = n * 16 + laneR;
    bo[n] = col * 128 + (kb2 ^ ((col & 7) << 4));
  }

  const f32x4 zero4 = {0.f, 0.f, 0.f, 0.f};
  f32x4 dotp[2], nqp[2], nkp[2];
  #pragma unroll
  for (int mt = 0; mt < 2; ++mt){ dotp[mt] = zero4; nqp[mt] = zero4; nkp[mt] = zero4; }

  for (int ei = 0; ei < 8; ++ei){
    const int e0 = (eh << 9) + (ei << 6);  // 64-col e-tile base
    f32x4 accq[2][4], acck[2][4];
    #pragma unroll
    for (int mt = 0; mt < 2; ++mt)
      #pragma unroll
      for (int n = 0; n < 4; ++n){ accq[mt][n] = zero4; acck[mt][n] = zero4; }

    for (int ks = 0; ks < 32; ++ks){
      const int kg = ks << 5;
      __syncthreads();
      // ---- stage x: 129 rows x 32 k (516 8-elem tasks)
      for (int task = tid; task < 516; task += 256){
        const int row = task >> 2, c8 = task & 3;
        const int grow = row0 - 1 + row + ((row == 0) ? firstAdj : 0);
        u32x4 hp, lp;
        cvt8(x + (size_t)grow * D_ + kg + c8 * 8, hp, lp);
        const int ho = row * 128 + ((c8 << 4) ^ ((row & 7) << 4));
        *(u32x4*)((char*)xhl + ho) = hp;
        *(u32x4*)((char*)xhl + (ho ^ 64)) = lp;
      }
      // ---- stage Wq/Wk: 2 x 64 cols x 32 k (512 tasks)
      for (int task = tid; task < 512; task += 256){
        const int mat = task >> 8, rem = task & 255, col = rem >> 2, c8 = rem & 3;
        const float* Wm = mat ? Wk : Wq;
        u32x4 hp, lp;
        cvt8(Wm + (size_t)(e0 + col) * D_ + kg + c8 * 8, hp, lp);
        unsigned short* plane = mat ? wkp : wqp;
        const int ho = col * 128 + ((c8 << 4) ^ ((col & 7) << 4));
        *(u32x4*)((char*)plane + ho) = hp;
        *(u32x4*)((char*)plane + (ho ^ 64)) = lp;
      }
      __syncthreads();

      short8 aqh[2], aql[2], akh[2], akl[2];
      #pragma unroll
      for (int mt = 0; mt < 2; ++mt){
        aqh[mt] = *(const short8*)((const char*)xhl + aoq[mt]);
        aql[mt] = *(const short8*)((const char*)xhl + (aoq[mt] ^ 64));
        akh[mt] = *(const short8*)((const char*)xhl + aok[mt]);
        akl[mt] = *(const short8*)((const char*)xhl + (aok[mt] ^ 64));
      }
      #pragma unroll
      for (int n = 0; n < 4; ++n){
        const short8 bqh = *(const short8*)((const char*)wqp + bo[n]);
        const short8 bql = *(const short8*)((const char*)wqp + (bo[n] ^ 64));
        const short8 bkh = *(const short8*)((const char*)wkp + bo[n]);
        const short8 bkl = *(const short8*)((const char*)wkp + (bo[n] ^ 64));
        #pragma unroll
        for (int mt = 0; mt < 2; ++mt){
          accq[mt][n] = __builtin_amdgcn_mfma_f32_16x16x32_bf16(aqh[mt], bqh, accq[mt][n], 0, 0, 0);
          accq[mt][n] = __builtin_amdgcn_mfma_f32_16x16x32_bf16(aqh[mt], bql, accq[mt][n], 0, 0, 0);
          accq[mt][n] = __builtin_amdgcn_mfma_f32_16x16x32_bf16(aql[mt], bqh, accq[mt][n], 0, 0, 0);
          acck[mt][n] = __builtin_amdgcn_mfma_f32_16x16x32_bf16(akh[mt], bkh, acck[mt][n], 0, 0, 0);
          acck[mt][n] = __builtin_amdgcn_mfma_f32_16x16x32_bf16(akh[mt], bkl, acck[mt][n], 0, 0, 0);
          acck[mt][n] = __builtin_amdgcn_mfma_f32_16x16x32_bf16(akl[mt], bkh, acck[mt][n], 0, 0, 0);
        }
      }
    }
    // fold this e-tile into per-row partial scalars (same C/D lane mapping for
    // q-tile and row-shifted k-tile => elementwise products are col-aligned)
    #pragma unroll
    for (int mt = 0; mt < 2; ++mt)
      #pragma unroll
      for (int n = 0; n < 4; ++n){
        dotp[mt] += accq[mt][n] * acck[mt][n];
        nqp[mt]  += accq[mt][n] * accq[mt][n];
        nkp[mt]  += acck[mt][n] * acck[mt][n];
      }
  }

  // reduce over the 16 cols held by the 16-lane group
  #pragma unroll
  for (int mt = 0; mt < 2; ++mt){
    #pragma unroll
    for (int m = 1; m < 16; m <<= 1){
      #pragma unroll
      for (int c = 0; c < 4; ++c){
        dotp[mt][c] += __shfl_xor(dotp[mt][c], m, 64);
        nqp[mt][c]  += __shfl_xor(nqp[mt][c], m, 64);
        nkp[mt][c]  += __shfl_xor(nkp[mt][c], m, 64);
      }
    }
  }
  if (laneR == 0){
    #pragma unroll
    for (int mt = 0; mt < 2; ++mt){
      #pragma unroll
      for (int r = 0; r < 4; ++r){
        const int grow = row0 + wv * 32 + mt * 16 + laneG * 4 + r;  // C/D row map
        const int idx = eh * BL + grow;
        dotS[idx] = dotp[mt][r];
        nqS[idx]  = nqp[mt][r];
        nkS[idx]  = nkp[mt][r];
      }
    }
  }
}

// ---------------------------------------------------------------------------
// K2: per-batch — combine e-half partials -> p, b; Hillis-Steele scan of b ->
// invmap (dest -> src), lengths, per-batch sums for F/G.
// ---------------------------------------------------------------------------
__global__ void k2_scan(const float* __restrict__ dotS, const float* __restrict__ nqS,
                        const float* __restrict__ nkS,
                        float* __restrict__ p_out, float* __restrict__ b_out,
                        float* __restrict__ len_out, int* __restrict__ invmap,
                        float* __restrict__ bat_sums, int* __restrict__ lenI)
{
  const int batch = blockIdx.x;
  const int tid   = threadIdx.x;  // 1024 threads, 8 rows each
  const int lbase = tid << 3;
  float ps = 0.f; int bc = 0; unsigned bits = 0;
  #pragma unroll
  for (int j = 0; j < 8; ++j){
    const int l = lbase + j;
    const int g = batch * L_ + l;
    const float dt = dotS[g] + dotS[BL + g];
    const float nq = nqS[g] + nqS[BL + g];
    const float nk = nkS[g] + nkS[BL + g];
    float p;
    if (l == 0) p = 1.f;
    else {
      const float dn = fmaxf(sqrtf(nq), 1e-12f) * fmaxf(sqrtf(nk), 1e-12f);
      p = 0.5f * (1.f - dt / dn);
    }
    const int bb = (p >= 0.5f) ? 1 : 0;
    p_out[g] = p;
    b_out[g] = (float)bb;
    ps += p; bc += bb; bits |= (unsigned)bb << j;
  }
  __shared__ int iw[1024];
  __shared__ float fw[1024];
  iw[tid] = bc;
  __syncthreads();
  for (int off = 1; off < 1024; off <<= 1){
    int v = (tid >= off) ? iw[tid - off] : 0;
    __syncthreads();
    iw[tid] += v;
    __syncthreads();
  }
  int run = iw[tid] - bc;                 // exclusive prefix
  const int total = iw[1023];
  #pragma unroll
  for (int j = 0; j < 8; ++j){
    if ((bits >> j) & 1u){ invmap[batch * L_ + run] = lbase + j; ++run; }
  }
  fw[tid] = ps;
  __syncthreads();
  for (int s = 512; s > 0; s >>= 1){
    if (tid < s) fw[tid] += fw[tid + s];
    __syncthreads();
  }
  if (tid == 0){
    bat_sums[batch]     = (float)total;   // sum of b
    bat_sums[4 + batch] = fw[0];          // sum of p
    lenI[batch]    = total;
    len_out[batch] = (float)total;
  }
}

// ---------------------------------------------------------------------------
// K3: gather-compact. One block per destination slot (b, j): copy x row
// invmap[j] (or zeros), P_down scalar; block (0,0) writes ratio_loss.
// Every output element is written exactly once (poison-safe).
// ---------------------------------------------------------------------------
__global__ void k3_fill(const float* __restrict__ x, const float* __restrict__ p_out,
                        const int* __restrict__ invmap, const int* __restrict__ lenI,
                        const float* __restrict__ bat_sums,
                        float* __restrict__ xdown, float* __restrict__ Pdown,
                        float* __restrict__ loss_out)
{
  const int j     = blockIdx.x;
  const int batch = blockIdx.y;
  const int tid   = threadIdx.x;  // 256, one f32x4 each
  const int len   = lenI[batch];
  const int inb   = (j < len) ? 1 : 0;
  const int src   = inb ? invmap[batch * L_ + j] : 0;
  f32x4 v = {0.f, 0.f, 0.f, 0.f};
  if (inb) v = *(const f32x4*)(x + (((size_t)(batch * L_ + src)) << 10) + (tid << 2));
  *(f32x4*)(xdown + (((size_t)(batch * L_ + j)) << 10) + (tid << 2)) = v;
  if (tid == 0){
    Pdown[batch * L_ + j] = inb ? p_out[batch * L_ + src] : 0.f;
    if (batch == 0 && j == 0){
      const float F = (bat_sums[0] + bat_sums[1] + bat_sums[2] + bat_sums[3]) * (1.f / 32768.f);
      const float G = (bat_sums[4] + bat_sums[5] + bat_sums[6] + bat_sums[7]) * (1.f / 32768.f);
      loss_out[0] = 1.2f * (5.f * F * G + (1.f - F) * (1.f - G));  // N=6
    }
  }
}

extern "C" void kernel_launch(void* const* d_in, const int* in_sizes, int n_in,
                              void* d_out, int out_size, void* d_ws, size_t ws_size,
                              hipStream_t stream)
{
  const float* x  = (const float*)d_in[0];
  const float* Wq = (const float*)d_in[1];
  const float* Wk = (const float*)d_in[2];

  float* out      = (float*)d_out;
  float* xdown    = out;                         // (B, L, D)
  float* Pdown    = out + (size_t)BL * D_;       // (B, L)
  float* b_out    = Pdown + BL;                  // (B, L)
  float* p_out    = b_out + BL;                  // (B, L)
  float* len_out  = p_out + BL;                  // (B,)
  float* loss_out = len_out + B_;                // scalar

  float* dotS     = (float*)d_ws;                // [2][BL]
  float* nqS      = dotS + 2 * BL;               // [2][BL]
  float* nkS      = nqS + 2 * BL;                // [2][BL]
  int*   invmap   = (int*)(nkS + 2 * BL);        // [B][L]
  float* bat_sums = (float*)(invmap + BL);       // [8]
  int*   lenI     = (int*)(bat_sums + 8);        // [4]

  hipLaunchKernelGGL(k1_qkdot, dim3(256, 2), dim3(256), 0, stream,
                     x, Wq, Wk, dotS, nqS, nkS);
  hipLaunchKernelGGL(k2_scan, dim3(4), dim3(1024), 0, stream,
                     dotS, nqS, nkS, p_out, b_out, len_out, invmap, bat_sums, lenI);
  hipLaunchKernelGGL(k3_fill, dim3(8192, 4), dim3(256), 0, stream,
                     x, p_out, invmap, lenI, bat_sums, xdown, Pdown, loss_out);
}

// Round 2
// 726.887 us; speedup vs baseline: 1.4276x; 1.4276x over previous
//
#include <hip/hip_runtime.h>
#include <stdint.h>
#include <stddef.h>

typedef __attribute__((ext_vector_type(8))) short short8;
typedef __attribute__((ext_vector_type(16))) float f32x16;
typedef __attribute__((ext_vector_type(4))) float f32x4;
typedef __attribute__((ext_vector_type(4))) unsigned int u32x4;

#define B_ 4
#define L_ 8192
#define D_ 1024
#define BL 32768
#define XROWS 32769  // 1 pad row + 32768

__device__ __forceinline__ unsigned bf16rne(float v){
  unsigned u = __float_as_uint(v);
  return (u + 0x7fffu + ((u >> 16) & 1u)) >> 16;
}

__device__ __forceinline__ void gload16(const void* g, void* l){
  __builtin_amdgcn_global_load_lds((const __attribute__((address_space(1))) void*)g,
                                   (__attribute__((address_space(3))) void*)l, 16, 0, 0);
}

// ---------------------------------------------------------------------------
// K0: convert f32 matrix [nrows][1024] into packed bf16 hi/lo layout:
// dst 16B units at ((ks*8 + c)*rowstride + pad + row)*16, where chunk c<4 holds
// hi bf16 of k_local = c*8..c*8+7 (k = ks*32 + k_local), c>=4 holds lo of
// (c-4)*8.. . This matches both global_load_lds linear staging and the
// mfma_32x32x16 fragment read pattern (lane = row, k-group = lane>>5).
// ---------------------------------------------------------------------------
__global__ void k0_cvt(const float* __restrict__ src, unsigned char* __restrict__ dst,
                       int rowstride, int pad)
{
  __shared__ unsigned short hi[64][128];
  __shared__ unsigned short lo[64][128];
  const int rt = blockIdx.x;      // 64-row tile
  const int kt = blockIdx.y;      // 128-k tile
  const int tid = threadIdx.x;    // 256
  #pragma unroll
  for (int it = 0; it < 8; ++it){
    int idx = it*256 + tid;       // 2048 f32x4 loads
    int r = idx >> 5, q4 = idx & 31;
    f32x4 v = *(const f32x4*)(src + (size_t)(rt*64 + r)*1024 + kt*128 + q4*4);
    #pragma unroll
    for (int j = 0; j < 4; ++j){
      float f = v[j];
      unsigned h = bf16rne(f);
      float hf = __uint_as_float(h << 16);
      unsigned lw = bf16rne(f - hf);
      hi[r][q4*4+j] = (unsigned short)h;
      lo[r][q4*4+j] = (unsigned short)lw;
    }
  }
  __syncthreads();
  #pragma unroll
  for (int it = 0; it < 8; ++it){
    int seg = it*4 + (tid>>6);    // 0..31 : (ks_local 0..3, c 0..7)
    int r = tid & 63;
    int ksl = seg >> 3;
    int c = seg & 7;
    const unsigned short* plane = (c < 4) ? &hi[0][0] : &lo[0][0];
    int kl = ksl*32 + (c & 3)*8;
    u32x4 val = *(const u32x4*)(plane + r*128 + kl);
    int ksg = kt*4 + ksl;
    size_t off = (((size_t)(ksg*8 + c)) * rowstride + (pad + rt*64 + r)) * 16;
    *(u32x4*)(dst + off) = val;
  }
}

// ---------------------------------------------------------------------------
// K1 fast: fused dual-GEMM with per-row scalar reduction.
// Grid 2048: strip = (bid&7) + 8*(bid>>6)  (same-strip blocks share an XCD),
// echunk = (bid>>3)&7. Block: 256 thr = 4 waves (2M x 2N), wave tile 64x64,
// mfma_f32_32x32x16_bf16, 3-term hi/lo split (hh + hl + lh).
// LDS: x 8 planes x 2064B (129 rows) | Wq 8 x 2048B | Wk 8 x 2048B = 49280 B.
// ---------------------------------------------------------------------------
__launch_bounds__(256, 2)
__global__ void k1_fast(const unsigned char* __restrict__ xcv,
                        const unsigned char* __restrict__ wqcv,
                        const unsigned char* __restrict__ wkcv,
                        float* __restrict__ dotS, float* __restrict__ nqS,
                        float* __restrict__ nkS)
{
  __shared__ __align__(16) unsigned char lds[49280];
  const int tid = threadIdx.x, lane = tid & 63, w = tid >> 6;
  const int wr = w >> 1, wc = w & 1;
  const int bid = blockIdx.x;
  const int strip = (bid & 7) + ((bid >> 6) << 3);
  const int echunk = (bid >> 3) & 7;
  const int row0 = strip << 7;
  const int col0 = echunk << 7;
  const int l31 = lane & 31, lh = lane >> 5;

  // staging chunks: 24 x (3 per plane: 0..1023, 1024..2047, 1040..2063),
  // 16 wq, 16 wk. Wave w: x chunks w*6+j (j<6), wq w*4+(j-6), wk w*4+(j-10).
  unsigned goff[14], loff[14];
  #pragma unroll
  for (int j = 0; j < 6; ++j){
    int i = w*6 + j; int c = i/3; int part = i - c*3;
    unsigned s = (part == 0) ? 0u : (part == 1 ? 1024u : 1040u);
    goff[j] = ((unsigned)c*XROWS + (unsigned)row0)*16u + s + (unsigned)lane*16u;
    loff[j] = (unsigned)c*2064u + s + (unsigned)lane*16u;
  }
  #pragma unroll
  for (int j = 6; j < 10; ++j){
    int i = w*4 + (j-6); int c = i >> 1, h = i & 1;
    goff[j] = ((unsigned)c*1024u + (unsigned)col0)*16u + (unsigned)h*1024u + (unsigned)lane*16u;
    loff[j] = 16512u + (unsigned)c*2048u + (unsigned)h*1024u + (unsigned)lane*16u;
  }
  #pragma unroll
  for (int j = 10; j < 14; ++j){
    int i = w*4 + (j-10); int c = i >> 1, h = i & 1;
    goff[j] = ((unsigned)c*1024u + (unsigned)col0)*16u + (unsigned)h*1024u + (unsigned)lane*16u;
    loff[j] = 32896u + (unsigned)c*2048u + (unsigned)h*1024u + (unsigned)lane*16u;
  }

  // fragment read bases (byte offsets into lds). plane strides: x 2064, W 2048.
  const unsigned bq  = (unsigned)(wr*64 + l31 + 1)*16u + (unsigned)lh*2064u;  // q: rows +1
  const unsigned bk  = bq - 16u;                                              // k: rows +0
  const unsigned bwq = 16512u + (unsigned)(wc*64 + l31)*16u + (unsigned)lh*2048u;
  const unsigned bwk = bwq + 16384u;

  f32x16 accq[2][2] = {}, acck[2][2] = {};

  for (int ks = 0; ks < 32; ++ks){
    __syncthreads();
    #pragma unroll
    for (int j = 0; j < 14; ++j){
      const unsigned char* gb = (j < 6) ? xcv : (j < 10 ? wqcv : wkcv);
      gload16(gb + goff[j], lds + loff[j]);
      goff[j] += (j < 6) ? 4194432u : 131072u;
    }
    __syncthreads();
    #pragma unroll
    for (int kk = 0; kk < 2; ++kk){
      short8 aq[2][2], ak[2][2];   // [mt][hi/lo]
      #pragma unroll
      for (int mt = 0; mt < 2; ++mt)
        #pragma unroll
        for (int hl = 0; hl < 2; ++hl){
          aq[mt][hl] = *(const short8*)(lds + bq + mt*512 + kk*4128 + hl*8256);
          ak[mt][hl] = *(const short8*)(lds + bk + mt*512 + kk*4128 + hl*8256);
        }
      #pragma unroll
      for (int n = 0; n < 2; ++n){
        short8 bqh = *(const short8*)(lds + bwq + n*512 + kk*4096);
        short8 bql = *(const short8*)(lds + bwq + n*512 + kk*4096 + 8192);
        short8 bkh = *(const short8*)(lds + bwk + n*512 + kk*4096);
        short8 bkl = *(const short8*)(lds + bwk + n*512 + kk*4096 + 8192);
        #pragma unroll
        for (int mt = 0; mt < 2; ++mt){
          accq[mt][n] = __builtin_amdgcn_mfma_f32_32x32x16_bf16(aq[mt][0], bqh, accq[mt][n], 0, 0, 0);
          accq[mt][n] = __builtin_amdgcn_mfma_f32_32x32x16_bf16(aq[mt][0], bql, accq[mt][n], 0, 0, 0);
          accq[mt][n] = __builtin_amdgcn_mfma_f32_32x32x16_bf16(aq[mt][1], bqh, accq[mt][n], 0, 0, 0);
          acck[mt][n] = __builtin_amdgcn_mfma_f32_32x32x16_bf16(ak[mt][0], bkh, acck[mt][n], 0, 0, 0);
          acck[mt][n] = __builtin_amdgcn_mfma_f32_32x32x16_bf16(ak[mt][0], bkl, acck[mt][n], 0, 0, 0);
          acck[mt][n] = __builtin_amdgcn_mfma_f32_32x32x16_bf16(ak[mt][1], bkh, acck[mt][n], 0, 0, 0);
        }
      }
    }
  }

  // fold: elementwise products are (row,col)-aligned between q and row-shifted k
  #pragma unroll
  for (int mt = 0; mt < 2; ++mt){
    f32x16 dv = accq[mt][0]*acck[mt][0] + accq[mt][1]*acck[mt][1];
    f32x16 qv = accq[mt][0]*accq[mt][0] + accq[mt][1]*accq[mt][1];
    f32x16 kv = acck[mt][0]*acck[mt][0] + acck[mt][1]*acck[mt][1];
    #pragma unroll
    for (int m = 1; m < 32; m <<= 1){
      #pragma unroll
      for (int r = 0; r < 16; ++r){
        dv[r] += __shfl_xor(dv[r], m, 64);
        qv[r] += __shfl_xor(qv[r], m, 64);
        kv[r] += __shfl_xor(kv[r], m, 64);
      }
    }
    if (l31 == 0){
      #pragma unroll
      for (int r = 0; r < 16; ++r){
        int rm = (r & 3) + ((r >> 2) << 3) + (lh << 2);   // C/D row map 32x32
        int grow = row0 + wr*64 + mt*32 + rm;
        size_t idx = (size_t)echunk * BL + grow;
        dotS[idx] = dv[r]; nqS[idx] = qv[r]; nkS[idx] = kv[r];
      }
    }
  }
}

// ---------------------------------------------------------------------------
// K1 old (fallback when ws too small): round-1 kernel, in-loop conversion.
// ---------------------------------------------------------------------------
__device__ __forceinline__ void cvt8(const float* __restrict__ src, u32x4& hp, u32x4& lp){
  float v[8];
  *(f32x4*)(v)     = *(const f32x4*)(src);
  *(f32x4*)(v + 4) = *(const f32x4*)(src + 4);
  unsigned hb[8], lb[8];
  #pragma unroll
  for (int j = 0; j < 8; ++j){
    hb[j] = bf16rne(v[j]);
    float hif = __uint_as_float(hb[j] << 16);
    lb[j] = bf16rne(v[j] - hif);
  }
  #pragma unroll
  for (int t = 0; t < 4; ++t){
    hp[t] = hb[2*t] | (hb[2*t+1] << 16);
    lp[t] = lb[2*t] | (lb[2*t+1] << 16);
  }
}

__launch_bounds__(256, 2)
__global__ void k1_old(const float* __restrict__ x, const float* __restrict__ Wq,
                       const float* __restrict__ Wk,
                       float* __restrict__ dotS, float* __restrict__ nqS,
                       float* __restrict__ nkS)
{
  __shared__ __align__(16) unsigned short lds[(129 + 64 + 64) * 64];
  unsigned short* xhl = lds;
  unsigned short* wqp = lds + 129 * 64;
  unsigned short* wkp = wqp + 64 * 64;

  const int tid   = threadIdx.x;
  const int strip = blockIdx.x;
  const int eh    = blockIdx.y;
  const int row0  = strip << 7;
  const int firstAdj = ((row0 & (L_ - 1)) == 0) ? 1 : 0;

  const int lane  = tid & 63;
  const int wv    = tid >> 6;
  const int laneR = lane & 15;
  const int laneG = lane >> 4;
  const int kb2   = laneG << 4;

  int aoq[2], aok[2];
  #pragma unroll
  for (int mt = 0; mt < 2; ++mt){
    const int qrow = wv * 32 + mt * 16 + laneR + 1;
    const int krow = qrow - 1;
    aoq[mt] = qrow * 128 + (kb2 ^ ((qrow & 7) << 4));
    aok[mt] = krow * 128 + (kb2 ^ ((krow & 7) << 4));
  }
  int bo[4];
  #pragma unroll
  for (int n = 0; n < 4; ++n){
    const int col = n * 16 + laneR;
    bo[n] = col * 128 + (kb2 ^ ((col & 7) << 4));
  }

  const f32x4 zero4 = {0.f, 0.f, 0.f, 0.f};
  f32x4 dotp[2], nqp[2], nkp[2];
  #pragma unroll
  for (int mt = 0; mt < 2; ++mt){ dotp[mt] = zero4; nqp[mt] = zero4; nkp[mt] = zero4; }

  for (int ei = 0; ei < 8; ++ei){
    const int e0 = (eh << 9) + (ei << 6);
    f32x4 accq[2][4], acck[2][4];
    #pragma unroll
    for (int mt = 0; mt < 2; ++mt)
      #pragma unroll
      for (int n = 0; n < 4; ++n){ accq[mt][n] = zero4; acck[mt][n] = zero4; }

    for (int ksi = 0; ksi < 32; ++ksi){
      const int kg = ksi << 5;
      __syncthreads();
      for (int task = tid; task < 516; task += 256){
        const int row = task >> 2, c8 = task & 3;
        const int grow = row0 - 1 + row + ((row == 0) ? firstAdj : 0);
        u32x4 hp, lp;
        cvt8(x + (size_t)grow * D_ + kg + c8 * 8, hp, lp);
        const int ho = row * 128 + ((c8 << 4) ^ ((row & 7) << 4));
        *(u32x4*)((char*)xhl + ho) = hp;
        *(u32x4*)((char*)xhl + (ho ^ 64)) = lp;
      }
      for (int task = tid; task < 512; task += 256){
        const int mat = task >> 8, rem = task & 255, col = rem >> 2, c8 = rem & 3;
        const float* Wm = mat ? Wk : Wq;
        u32x4 hp, lp;
        cvt8(Wm + (size_t)(e0 + col) * D_ + kg + c8 * 8, hp, lp);
        unsigned short* plane = mat ? wkp : wqp;
        const int ho = col * 128 + ((c8 << 4) ^ ((col & 7) << 4));
        *(u32x4*)((char*)plane + ho) = hp;
        *(u32x4*)((char*)plane + (ho ^ 64)) = lp;
      }
      __syncthreads();

      short8 aqh[2], aql[2], akh[2], akl[2];
      #pragma unroll
      for (int mt = 0; mt < 2; ++mt){
        aqh[mt] = *(const short8*)((const char*)xhl + aoq[mt]);
        aql[mt] = *(const short8*)((const char*)xhl + (aoq[mt] ^ 64));
        akh[mt] = *(const short8*)((const char*)xhl + aok[mt]);
        akl[mt] = *(const short8*)((const char*)xhl + (aok[mt] ^ 64));
      }
      #pragma unroll
      for (int n = 0; n < 4; ++n){
        const short8 bqh = *(const short8*)((const char*)wqp + bo[n]);
        const short8 bql = *(const short8*)((const char*)wqp + (bo[n] ^ 64));
        const short8 bkh = *(const short8*)((const char*)wkp + bo[n]);
        const short8 bkl = *(const short8*)((const char*)wkp + (bo[n] ^ 64));
        #pragma unroll
        for (int mt = 0; mt < 2; ++mt){
          accq[mt][n] = __builtin_amdgcn_mfma_f32_16x16x32_bf16(aqh[mt], bqh, accq[mt][n], 0, 0, 0);
          accq[mt][n] = __builtin_amdgcn_mfma_f32_16x16x32_bf16(aqh[mt], bql, accq[mt][n], 0, 0, 0);
          accq[mt][n] = __builtin_amdgcn_mfma_f32_16x16x32_bf16(aql[mt], bqh, accq[mt][n], 0, 0, 0);
          acck[mt][n] = __builtin_amdgcn_mfma_f32_16x16x32_bf16(akh[mt], bkh, acck[mt][n], 0, 0, 0);
          acck[mt][n] = __builtin_amdgcn_mfma_f32_16x16x32_bf16(akh[mt], bkl, acck[mt][n], 0, 0, 0);
          acck[mt][n] = __builtin_amdgcn_mfma_f32_16x16x32_bf16(akl[mt], bkh, acck[mt][n], 0, 0, 0);
        }
      }
    }
    #pragma unroll
    for (int mt = 0; mt < 2; ++mt)
      #pragma unroll
      for (int n = 0; n < 4; ++n){
        dotp[mt] += accq[mt][n] * acck[mt][n];
        nqp[mt]  += accq[mt][n] * accq[mt][n];
        nkp[mt]  += acck[mt][n] * acck[mt][n];
      }
  }

  #pragma unroll
  for (int mt = 0; mt < 2; ++mt){
    #pragma unroll
    for (int m = 1; m < 16; m <<= 1){
      #pragma unroll
      for (int c = 0; c < 4; ++c){
        dotp[mt][c] += __shfl_xor(dotp[mt][c], m, 64);
        nqp[mt][c]  += __shfl_xor(nqp[mt][c], m, 64);
        nkp[mt][c]  += __shfl_xor(nkp[mt][c], m, 64);
      }
    }
  }
  if (laneR == 0){
    #pragma unroll
    for (int mt = 0; mt < 2; ++mt){
      #pragma unroll
      for (int r = 0; r < 4; ++r){
        const int grow = row0 + wv * 32 + mt * 16 + laneG * 4 + r;
        const int idx = eh * BL + grow;
        dotS[idx] = dotp[mt][r];
        nqS[idx]  = nqp[mt][r];
        nkS[idx]  = nkp[mt][r];
      }
    }
  }
}

// ---------------------------------------------------------------------------
// K2: combine partials -> p,b; wave-level scan -> invmap, lengths, sums.
// ---------------------------------------------------------------------------
__global__ void k2_scan(const float* __restrict__ dotS, const float* __restrict__ nqS,
                        const float* __restrict__ nkS,
                        float* __restrict__ p_out, float* __restrict__ b_out,
                        float* __restrict__ len_out, int* __restrict__ invmap,
                        float* __restrict__ bat_sums, int* __restrict__ lenI, int nparts)
{
  const int batch = blockIdx.x;
  const int tid   = threadIdx.x;  // 1024
  const int lane  = tid & 63, wv = tid >> 6;  // 16 waves
  const int lbase = tid << 3;
  float ps = 0.f; int bc = 0; unsigned bits = 0;
  #pragma unroll
  for (int j = 0; j < 8; ++j){
    const int l = lbase + j;
    const int g = batch * L_ + l;
    float dt = 0.f, nq = 0.f, nk = 0.f;
    for (int e = 0; e < nparts; ++e){
      dt += dotS[(size_t)e*BL + g]; nq += nqS[(size_t)e*BL + g]; nk += nkS[(size_t)e*BL + g];
    }
    float p;
    if (l == 0) p = 1.f;
    else {
      const float dn = fmaxf(sqrtf(nq), 1e-12f) * fmaxf(sqrtf(nk), 1e-12f);
      p = 0.5f * (1.f - dt / dn);
    }
    const int bb = (p >= 0.5f) ? 1 : 0;
    p_out[g] = p;
    b_out[g] = (float)bb;
    ps += p; bc += bb; bits |= (unsigned)bb << j;
  }
  // wave inclusive scan of bc
  int sc = bc;
  #pragma unroll
  for (int m = 1; m < 64; m <<= 1){
    int t = __shfl_up(sc, m, 64);
    if (lane >= m) sc += t;
  }
  float pss = ps;
  #pragma unroll
  for (int m = 1; m < 64; m <<= 1) pss += __shfl_xor(pss, m, 64);

  __shared__ int wsum[16];
  __shared__ float wps[16];
  if (lane == 63) wsum[wv] = sc;
  if (lane == 0)  wps[wv] = pss;
  __syncthreads();
  if (tid < 16){
    int v = wsum[tid];
    #pragma unroll
    for (int m = 1; m < 16; m <<= 1){
      int t = __shfl_up(v, m, 64);
      if (tid >= m) v += t;
    }
    wsum[tid] = v;
  }
  __syncthreads();
  const int waveoff = (wv == 0) ? 0 : wsum[wv - 1];
  const int total = wsum[15];
  int run = waveoff + sc - bc;   // exclusive prefix
  #pragma unroll
  for (int j = 0; j < 8; ++j){
    if ((bits >> j) & 1u){ invmap[batch * L_ + run] = lbase + j; ++run; }
  }
  if (tid == 0){
    float psum = 0.f;
    #pragma unroll
    for (int i = 0; i < 16; ++i) psum += wps[i];
    bat_sums[batch]     = (float)total;
    bat_sums[4 + batch] = psum;
    lenI[batch]    = total;
    len_out[batch] = (float)total;
  }
}

// ---------------------------------------------------------------------------
// K3: gather-compact (every output element written exactly once).
// ---------------------------------------------------------------------------
__global__ void k3_fill(const float* __restrict__ x, const float* __restrict__ p_out,
                        const int* __restrict__ invmap, const int* __restrict__ lenI,
                        const float* __restrict__ bat_sums,
                        float* __restrict__ xdown, float* __restrict__ Pdown,
                        float* __restrict__ loss_out)
{
  const int j     = blockIdx.x;
  const int batch = blockIdx.y;
  const int tid   = threadIdx.x;
  const int len   = lenI[batch];
  const int inb   = (j < len) ? 1 : 0;
  const int src   = inb ? invmap[batch * L_ + j] : 0;
  f32x4 v = {0.f, 0.f, 0.f, 0.f};
  if (inb) v = *(const f32x4*)(x + (((size_t)(batch * L_ + src)) << 10) + (tid << 2));
  *(f32x4*)(xdown + (((size_t)(batch * L_ + j)) << 10) + (tid << 2)) = v;
  if (tid == 0){
    Pdown[batch * L_ + j] = inb ? p_out[batch * L_ + src] : 0.f;
    if (batch == 0 && j == 0){
      const float F = (bat_sums[0] + bat_sums[1] + bat_sums[2] + bat_sums[3]) * (1.f / 32768.f);
      const float G = (bat_sums[4] + bat_sums[5] + bat_sums[6] + bat_sums[7]) * (1.f / 32768.f);
      loss_out[0] = 1.2f * (5.f * F * G + (1.f - F) * (1.f - G));
    }
  }
}

extern "C" void kernel_launch(void* const* d_in, const int* in_sizes, int n_in,
                              void* d_out, int out_size, void* d_ws, size_t ws_size,
                              hipStream_t stream)
{
  const float* x  = (const float*)d_in[0];
  const float* Wq = (const float*)d_in[1];
  const float* Wk = (const float*)d_in[2];

  float* out      = (float*)d_out;
  float* xdown    = out;
  float* Pdown    = out + (size_t)BL * D_;
  float* b_out    = Pdown + BL;
  float* p_out    = b_out + BL;
  float* len_out  = p_out + BL;
  float* loss_out = len_out + B_;

  const size_t XCV = (size_t)32*8*XROWS*16;   // 134,221,824
  const size_t WCV = (size_t)32*8*1024*16;    //   4,194,304
  const size_t need = XCV + 2*WCV + (size_t)3*8*BL*4 + (size_t)BL*4 + 1024;

  if (ws_size >= need){
    unsigned char* xcv  = (unsigned char*)d_ws;
    unsigned char* wqcv = xcv + XCV;
    unsigned char* wkcv = wqcv + WCV;
    float* dotS     = (float*)(wkcv + WCV);        // [8][BL]
    float* nqS      = dotS + (size_t)8*BL;
    float* nkS      = nqS + (size_t)8*BL;
    int*   invmap   = (int*)(nkS + (size_t)8*BL);  // [B][L]
    float* bat_sums = (float*)(invmap + BL);       // [8]
    int*   lenI     = (int*)(bat_sums + 8);        // [4]

    hipLaunchKernelGGL(k0_cvt, dim3(512, 8), dim3(256), 0, stream, x,  xcv,  XROWS, 1);
    hipLaunchKernelGGL(k0_cvt, dim3(16, 8),  dim3(256), 0, stream, Wq, wqcv, 1024,  0);
    hipLaunchKernelGGL(k0_cvt, dim3(16, 8),  dim3(256), 0, stream, Wk, wkcv, 1024,  0);
    hipLaunchKernelGGL(k1_fast, dim3(2048), dim3(256), 0, stream,
                       xcv, wqcv, wkcv, dotS, nqS, nkS);
    hipLaunchKernelGGL(k2_scan, dim3(4), dim3(1024), 0, stream,
                       dotS, nqS, nkS, p_out, b_out, len_out, invmap, bat_sums, lenI, 8);
    hipLaunchKernelGGL(k3_fill, dim3(8192, 4), dim3(256), 0, stream,
                       x, p_out, invmap, lenI, bat_sums, xdown, Pdown, loss_out);
  } else {
    float* dotS     = (float*)d_ws;                // [2][BL]
    float* nqS      = dotS + (size_t)2*BL;
    float* nkS      = nqS + (size_t)2*BL;
    int*   invmap   = (int*)(nkS + (size_t)2*BL);
    float* bat_sums = (float*)(invmap + BL);
    int*   lenI     = (int*)(bat_sums + 8);

    hipLaunchKernelGGL(k1_old, dim3(256, 2), dim3(256), 0, stream,
                       x, Wq, Wk, dotS, nqS, nkS);
    hipLaunchKernelGGL(k2_scan, dim3(4), dim3(1024), 0, stream,
                       dotS, nqS, nkS, p_out, b_out, len_out, invmap, bat_sums, lenI, 2);
    hipLaunchKernelGGL(k3_fill, dim3(8192, 4), dim3(256), 0, stream,
                       x, p_out, invmap, lenI, bat_sums, xdown, Pdown, loss_out);
  }
}